// Round 7
// baseline (27.917 us; speedup 1.0000x reference)
//
#include <hip/hip_runtime.h>

// PatchLoss: B=64, H=W=512, p=8 -> per batch 4096 patches of 64 elems.
// argmax_p sum|o-t| vs argmax_p sum(t) (mean = sum/64, argmax-invariant).
// Outputs {64, num_true, 64-num_true, num_true/64} as float32.
//
// R7 structure: async-DMA streaming. 512 blocks x 128 thr (2 waves/block).
// Wave g (0..1023) owns batch g>>4, slot s=g&15, tiles hb = s+16k (k=0..7);
// tile = half-band (8 rows x 256 cols) of BOTH inputs = 16KB.
// global_load_lds_dwordx4 DMAs each tile into a per-wave 2x16KB LDS
// ping-pong; counted s_waitcnt vmcnt(16) => 16-32KB in flight per wave at
// all times, immune to the register-pressure heuristic that capped MLP at
// ~6 loads in R2-R6 (VGPR_Count stuck at 20-36).

typedef unsigned long long u64;

__device__ __forceinline__ unsigned ordf(float f) {
    unsigned u = __float_as_uint(f);
    return u ^ ((u >> 31) ? 0xFFFFFFFFu : 0x80000000u);
}

__device__ __forceinline__ u64 umax64(u64 a, u64 b) { return a > b ? a : b; }

// Async global->LDS DMA, 16B per lane. LDS dest is wave-uniform base
// (HW adds lane*16); global src is per-lane.
#define GLDS(gp, lp)                                                      \
    __builtin_amdgcn_global_load_lds(                                     \
        (const __attribute__((address_space(1))) void*)(gp),              \
        (__attribute__((address_space(3))) void*)(lp), 16, 0, 0)

// Issue one tile's 16 DMAs: rows 0..7 of o -> buf[0..2047], rows of t ->
// buf[2048..4095] (float offsets; 1KB per row-chunk).
__device__ __forceinline__ void dma_tile(const float* po, const float* pt,
                                         float* buf) {
#pragma unroll
    for (int r = 0; r < 8; ++r)
        GLDS(po + (size_t)r * 512, buf + r * 256);
#pragma unroll
    for (int r = 0; r < 8; ++r)
        GLDS(pt + (size_t)r * 512, buf + 2048 + r * 256);
}

__device__ __forceinline__ void consume_lds(const float* buf, int l, int idx,
                                            u64& kl, u64& km) {
    const float4* f4 = (const float4*)buf;
    float sA = 0.f, sT = 0.f;
#pragma unroll
    for (int r = 0; r < 8; ++r) {
        const float4 o = f4[r * 64 + l];          // lane l: bytes r*1024+l*16
        const float4 g = f4[512 + r * 64 + l];
        sA += fabsf(o.x - g.x) + fabsf(o.y - g.y)
            + fabsf(o.z - g.z) + fabsf(o.w - g.w);
        sT += g.x + g.y + g.z + g.w;
    }
    // lanes l, l^1 hold the two float4 columns of one patch: combine.
    sA += __shfl_xor(sA, 1);
    sT += __shfl_xor(sT, 1);
    kl = umax64(kl, ((u64)ordf(sA) << 32) | (unsigned)(4095 - idx));
    km = umax64(km, ((u64)ordf(sT) << 32) | (unsigned)(4095 - idx));
}

__global__ __launch_bounds__(128)
void patch_kernel(const float* __restrict__ outp,
                  const float* __restrict__ tgt,
                  u64* __restrict__ wsL, u64* __restrict__ wsM) {
    __shared__ float smem[16384];                // 64KB: 2 waves x 2 x 16KB

    const int t   = threadIdx.x;                 // 0..127
    const int w01 = t >> 6;
    const int l   = t & 63;
    const int g   = blockIdx.x * 2 + w01;        // wave id 0..1023
    const int b   = g >> 4;                      // batch (16 waves/batch)
    const int s   = g & 15;                      // slot in batch

    float* buf0 = smem + w01 * 8192;
    float* buf1 = buf0 + 4096;

    // tile hb = s + 16k: ph = (s>>1)+8k, h = s&1 (parity constant in k).
    // base(k) = base0 + k*32768 floats.
    const size_t base0 = (size_t)b * 262144 + (size_t)(s >> 1) * 4096
                       + (size_t)(s & 1) * 256 + (size_t)l * 4;
    const float* po = outp + base0;
    const float* pt = tgt  + base0;
    const int idx0  = (s >> 1) * 64 + (s & 1) * 32 + (l >> 1);  // +512k per tile

    u64 kl = 0, km = 0;

    dma_tile(po, pt, buf0);                      // tile0: 16 outstanding
    dma_tile(po + 32768, pt + 32768, buf1);      // tile1: 32 outstanding

#pragma unroll
    for (int k = 0; k < 8; ++k) {
        if (k < 7) asm volatile("s_waitcnt vmcnt(16)" ::: "memory");
        else       asm volatile("s_waitcnt vmcnt(0)"  ::: "memory");
        __builtin_amdgcn_sched_barrier(0);

        float* cb = (k & 1) ? buf1 : buf0;
        consume_lds(cb, l, idx0 + 512 * k, kl, km);

        if (k < 6) {
            // ds_reads of cb must drain before DMA overwrites it (LDS DMA
            // writes are not ordered vs in-flight ds_read).
            asm volatile("s_waitcnt lgkmcnt(0)" ::: "memory");
            __builtin_amdgcn_sched_barrier(0);
            dma_tile(po + (size_t)(k + 2) * 32768,
                     pt + (size_t)(k + 2) * 32768, cb);
        }
    }

    // per-wave butterfly argmax (all candidates same-batch); s=1 skipped
    // (lane pairs hold identical candidates after the shfl combine).
#pragma unroll
    for (int sh = 32; sh > 1; sh >>= 1) {
        kl = umax64(kl, __shfl_xor(kl, sh));
        km = umax64(km, __shfl_xor(km, sh));
    }
    if (l == 0) { wsL[g] = kl; wsM[g] = km; }
}

__global__ void finalize_kernel(const u64* __restrict__ wsL,
                                const u64* __restrict__ wsM,
                                float* __restrict__ outp) {
    const int t    = threadIdx.x;  // 0..255
    const int q    = t >> 2;       // batch
    const int part = t & 3;

    u64 ml = 0, mm = 0;
    const int base = q * 16 + part * 4;
#pragma unroll
    for (int i = 0; i < 4; ++i) {
        ml = umax64(ml, wsL[base + i]);
        mm = umax64(mm, wsM[base + i]);
    }
    ml = umax64(ml, __shfl_xor(ml, 1));
    ml = umax64(ml, __shfl_xor(ml, 2));
    mm = umax64(mm, __shfl_xor(mm, 1));
    mm = umax64(mm, __shfl_xor(mm, 2));

    __shared__ int flags[64];
    if (part == 0)
        flags[q] = ((unsigned)ml == (unsigned)mm) ? 1 : 0;  // low32 = 4095-idx
    __syncthreads();

    if (t < 64) {
        int v = flags[t];
#pragma unroll
        for (int sh = 32; sh > 0; sh >>= 1) v += __shfl_down(v, sh);
        if (t == 0) {
            const float nt = (float)v;
            outp[0] = 64.0f;
            outp[1] = nt;
            outp[2] = 64.0f - nt;
            outp[3] = nt / 64.0f;
        }
    }
}

extern "C" void kernel_launch(void* const* d_in, const int* in_sizes, int n_in,
                              void* d_out, int out_size, void* d_ws, size_t ws_size,
                              hipStream_t stream) {
    const float* outp = (const float*)d_in[0];
    const float* tgt  = (const float*)d_in[1];
    // d_in[2] = patch_size (==8), hardcoded.

    u64* wsL = (u64*)d_ws;        // 1024 u64
    u64* wsM = wsL + 1024;        // 1024 u64

    patch_kernel<<<512, 128, 0, stream>>>(outp, tgt, wsL, wsM);
    finalize_kernel<<<1, 256, 0, stream>>>(wsL, wsM, (float*)d_out);
}